// Round 11
// baseline (549.299 us; speedup 1.0000x reference)
//
#include <hip/hip_runtime.h>
#include <cstdint>
#include <cstddef>

// ---------- problem constants ----------
#define BB   16
#define NN   4096
#define SS   1024
#define D1   128
#define D2   256
#define CIN  384
#define C0   256
#define C1   128
#define MM   (BB*NN)          // 65536
#define NGRID 512             // fused kernel grid: 256 CU x 2 blocks

typedef __attribute__((ext_vector_type(8))) short short8;
typedef __attribute__((ext_vector_type(4))) float f32x4;

__device__ __forceinline__ float b2f(unsigned short h) {
    union { unsigned int u; float f; } x; x.u = ((unsigned int)h) << 16; return x.f;
}
__device__ __forceinline__ unsigned short f2b(float f) {
    union { float f; unsigned int u; } x; x.f = f;
    unsigned int r = x.u + 0x7FFFu + ((x.u >> 16) & 1u);
    return (unsigned short)(r >> 16);
}

#define GLD16(g, l) __builtin_amdgcn_global_load_lds( \
    (const __attribute__((address_space(1))) void*)(g), \
    (__attribute__((address_space(3))) void*)(l), 16, 0, 0)

// agent-scope (device-coherent) accessors for cross-block data
__device__ __forceinline__ void ast(float* p, float v) {
    __hip_atomic_store(p, v, __ATOMIC_RELAXED, __HIP_MEMORY_SCOPE_AGENT);
}
__device__ __forceinline__ float ald(const float* p) {
    return __hip_atomic_load(p, __ATOMIC_RELAXED, __HIP_MEMORY_SCOPE_AGENT);
}

// grid barrier: all 512 blocks co-resident (2/CU by LDS+VGPR construction).
__device__ __forceinline__ void gridbar(unsigned* c) {
    __syncthreads();                       // compiler drains vmcnt before s_barrier
    if (threadIdx.x == 0) {
        __threadfence();
        atomicAdd(c, 1u);
        while (__hip_atomic_load(c, __ATOMIC_ACQUIRE, __HIP_MEMORY_SCOPE_AGENT) < (unsigned)NGRID)
            __builtin_amdgcn_s_sleep(2);
    }
    __syncthreads();
    __threadfence();
}

// ---------- knn v7: half-candidate blocks (512 cands each), f64 packed keys ----------
__device__ __forceinline__ void knn_body7(const float* __restrict__ xyz1,
                                          const float* __restrict__ xyz2,
                                          double* __restrict__ trip, float* __restrict__ wtb,
                                          int kb, int t, char* smem)
{
    float4* cnd = (float4*)smem;           // [8][65] float4, chunk-padded
    const int h    = kb & 1;
    const int pb   = kb >> 1;
    const int b    = pb >> 7;
    const int bx   = pb & 127;
    const int chunk = t & 7;
    const int n    = bx * 32 + (t >> 3);

    for (int i = t; i < 512; i += 256) {
        int s = h * 512 + i;
        float qx = xyz2[((size_t)b * 3 + 0) * SS + s];
        float qy = xyz2[((size_t)b * 3 + 1) * SS + s];
        float qz = xyz2[((size_t)b * 3 + 2) * SS + s];
        cnd[(i >> 6) * 65 + (i & 63)] = make_float4(qx, qy, qz, 0.f);
    }
    __syncthreads();

    const float px = xyz1[((size_t)b * 3 + 0) * NN + n];
    const float py = xyz1[((size_t)b * 3 + 1) * NN + n];
    const float pz = xyz1[((size_t)b * 3 + 2) * NN + n];

    const double INITK = __hiloint2double(0x7F7FFFFF, 0);
    double A0 = INITK, A1 = INITK, A2 = INITK;
    double B0 = INITK, B1 = INITK, B2 = INITK;
    const float4* cc = cnd + chunk * 65;
    const int sbase = h * 512 + chunk * 64;

#pragma unroll 4
    for (int c = 0; c < 64; c += 2) {
        {
            float4 q = cc[c];
            float dx = px - q.x, dy = py - q.y, dz = pz - q.z;
            float d = dx*dx + dy*dy + dz*dz;
            double k = __hiloint2double(__float_as_int(d), sbase + c);
            double t0 = fmin(k, A0), h0 = fmax(k, A0);
            double t1 = fmin(h0, A1), h1 = fmax(h0, A1);
            A2 = fmin(h1, A2); A0 = t0; A1 = t1;
        }
        {
            float4 q = cc[c + 1];
            float dx = px - q.x, dy = py - q.y, dz = pz - q.z;
            float d = dx*dx + dy*dy + dz*dz;
            double k = __hiloint2double(__float_as_int(d), sbase + c + 1);
            double t0 = fmin(k, B0), h0 = fmax(k, B0);
            double t1 = fmin(h0, B1), h1 = fmax(h0, B1);
            B2 = fmin(h1, B2); B0 = t0; B1 = t1;
        }
    }

    double K0, K1, K2;
    {
        double y0 = fmax(A0, B0);
        K0 = fmin(A0, B0);
        double x1 = fmin(A1, B1);
        K1 = fmin(y0, x1);
        double z  = fmax(y0, x1);
        K2 = fmin(z, fmin(A2, B2));
    }
#pragma unroll
    for (int r = 1; r <= 4; r <<= 1) {
        double C0d = __shfl_xor(K0, r);
        double C1d = __shfl_xor(K1, r);
        double C2d = __shfl_xor(K2, r);
        double y0 = fmax(K0, C0d);
        K0 = fmin(K0, C0d);
        double x1 = fmin(K1, C1d);
        double nK1 = fmin(y0, x1);
        double z  = fmax(y0, x1);
        K2 = fmin(z, fmin(K2, C2d));
        K1 = nK1;
    }

    if (chunk == 0) {
        size_t m = (size_t)b * NN + n;
        double* tp = trip + ((size_t)h * MM + m) * 3;
        tp[0] = K0; tp[1] = K1; tp[2] = K2;
        if (h == 0) {
            float4 q0 = cnd[0], q1 = cnd[1], q2 = cnd[2];
            float dd0, dd1, dd2;
            { float dx=px-q0.x, dy=py-q0.y, dz=pz-q0.z; dd0 = fmaxf(dx*dx+dy*dy+dz*dz, 1e-10f); }
            { float dx=px-q1.x, dy=py-q1.y, dz=pz-q1.z; dd1 = fmaxf(dx*dx+dy*dy+dz*dz, 1e-10f); }
            { float dx=px-q2.x, dy=py-q2.y, dz=pz-q2.z; dd2 = fmaxf(dx*dx+dy*dy+dz*dz, 1e-10f); }
            float r0 = 1.f/dd0, r1 = 1.f/dd1, r2 = 1.f/dd2;
            float inv = 1.f / (r0 + r1 + r2);
            wtb[m*3+0] = r0*inv; wtb[m*3+1] = r1*inv; wtb[m*3+2] = r2*inv;
        }
    }
}

__device__ __forceinline__ void transpose_body(const float* __restrict__ src,
                                               unsigned short* __restrict__ dst,
                                               int C, int Np, int dstStride,
                                               int b, int cblk, int nblk, int t, char* smem)
{
    float (*tile)[65] = (float(*)[65])smem;
    const int c0 = cblk * 64, n0 = nblk * 64;
    const int j = t & 63, i4 = t >> 6;
#pragma unroll
    for (int p = 0; p < 64; p += 4) {
        int ci = p + i4;
        tile[ci][j] = src[((size_t)b * C + c0 + ci) * Np + n0 + j];
    }
    __syncthreads();
#pragma unroll
    for (int p = 0; p < 64; p += 4) {
        int ni = p + i4;
        dst[((size_t)b * Np + n0 + ni) * dstStride + c0 + j] = f2b(tile[j][ni]);
    }
}

// ---------- mega front: knn halves + transposes + weight cvt (unchanged) ----------
__global__ __launch_bounds__(256) void mega_front_k(
    const float* __restrict__ xyz1, const float* __restrict__ xyz2,
    const float* __restrict__ points1, const float* __restrict__ points2,
    const float* __restrict__ w0, const float* __restrict__ w1,
    unsigned short* __restrict__ P1T, unsigned short* __restrict__ P2T,
    unsigned short* __restrict__ w0b, unsigned short* __restrict__ w1b,
    double* __restrict__ trip, float* __restrict__ wtb)
{
    __shared__ __align__(16) char smem[16640];
    const unsigned bid = blockIdx.x;
    const int g = bid / 118, r = bid % 118;
    const int t = threadIdx.x;

    if (r < 64) {
        knn_body7(xyz1, xyz2, trip, wtb, g * 64 + r, t, smem);
    } else if (r < 96) {
        int rb = g * 32 + (r - 64);
        transpose_body(points1, P1T, D1, NN, D1,
                       rb >> 7, (rb >> 6) & 1, rb & 63, t, smem);
    } else if (r < 112) {
        int rb = g * 16 + (r - 96);
        transpose_body(points2, P2T, D2, SS, D2,
                       rb >> 6, (rb >> 4) & 3, rb & 15, t, smem);
    } else {
        int rb = g * 6 + (r - 112);
        int i = rb * 256 + t;
        if (i < C0 * CIN) w0b[i] = f2b(w0[i]);
        if (i < C1 * C0)  w1b[i] = f2b(w1[i]);
    }
}

// ---------- fused mid: gemm1 + BN1 + gemm2 + BN2 + finalize, 4 grid barriers ----------
__launch_bounds__(512, 4)
__global__ void fused_mid_k(const unsigned short* __restrict__ P1T,
                            const unsigned short* __restrict__ P2T,
                            const double* __restrict__ trip, const float* __restrict__ wtb,
                            const unsigned short* __restrict__ w0b,
                            const unsigned short* __restrict__ w1b,
                            const float* __restrict__ g0, const float* __restrict__ be0,
                            const float* __restrict__ g1, const float* __restrict__ be1,
                            float* __restrict__ part1, float* __restrict__ part2g,
                            float* __restrict__ sc1, float* __restrict__ sh1,
                            float* __restrict__ sc2, float* __restrict__ sh2,
                            unsigned* __restrict__ bar, float* __restrict__ out)
{
    // LDS layout (66560 B total -> 2 blocks/CU):
    //   phase1: Bls 32KB @0, Als 16KB @32768, lsum/lsq 4KB @49152
    //   BN1/phase2: h1tile 64KB @0 (128 rows x 256 ch bf16, XOR-swizzled)
    //   phase2 epi: pst 4KB @0 ; phase3: trs [128][129] f32 @0
    __shared__ __align__(16) char lds[66560];
    unsigned short* BlsP = (unsigned short*)lds;
    char* AlsP = lds + 32768;
    float* lsumA = (float*)(lds + 49152);   // [2][256]
    float* lsqA  = (float*)(lds + 53248);   // [2][256]

    const int t = threadIdx.x;
    const int bid = blockIdx.x;
    const int wv = t >> 6, l = t & 63, g = l >> 4, lc = l & 15;
    const int wm = wv >> 2, wn = wv & 3;
    const int m0 = bid * 128;
    const int b  = bid >> 5;
    const int sub = t & 7;

    // ----- phase 1: GEMM1 (A: P1T + fused 3-NN interpolation; B: w0b) -----
    const int grow = t >> 2;
    const size_t gm = (size_t)(m0 + grow);
    const double* tpA = trip + gm * 3;
    const double* tpB = trip + ((size_t)MM + gm) * 3;
    double hA0 = tpA[0], hA1 = tpA[1], hA2 = tpA[2];
    double hB0 = tpB[0], hB1 = tpB[1], hB2 = tpB[2];
    double y0m = fmax(hA0, hB0), K0 = fmin(hA0, hB0);
    double x1m = fmin(hA1, hB1), K1 = fmin(y0m, x1m);
    double zm  = fmax(y0m, x1m), K2 = fmin(zm, fmin(hA2, hB2));
    const int gi0 = __double2loint(K0);
    const int gi1 = __double2loint(K1);
    const int gi2 = __double2loint(K2);
    const float gw0 = wtb[gm*3], gw1 = wtb[gm*3+1], gw2 = wtb[gm*3+2];
    const char* gp0 = (const char*)(P2T + ((size_t)b * SS + gi0) * D2) + (t & 3) * 32;
    const char* gp1 = (const char*)(P2T + ((size_t)b * SS + gi1) * D2) + (t & 3) * 32;
    const char* gp2 = (const char*)(P2T + ((size_t)b * SS + gi2) * D2) + (t & 3) * 32;
    char* gdst = AlsP + grow * 128;
    const int gsw = (grow & 7) << 4;

    f32x4 acc[4][4];
#pragma unroll
    for (int i = 0; i < 4; ++i)
#pragma unroll
        for (int j = 0; j < 4; ++j) acc[i][j] = (f32x4){0.f, 0.f, 0.f, 0.f};

    for (int ks = 0; ks < 6; ++ks) {
        const int k0 = ks * 64;
        __syncthreads();
        if (ks < 2) {
#pragma unroll
            for (int q = 0; q < 2; ++q) {
                int row = q * 64 + (t >> 3);
                int bco = (sub * 16) ^ ((row & 7) << 4);
                const char* src = (const char*)P1T + (((size_t)(m0 + row)) * D1 + k0) * 2 + bco;
                char* dst = AlsP + (q * 512 + wv * 64) * 16;
                GLD16(src, dst);
            }
        } else {
            const int cgB = (ks - 2) * 128;
#pragma unroll
            for (int hh = 0; hh < 2; ++hh) {
                union { uint4 v; unsigned short s[8]; } a0, a1, a2, ov;
                a0.v = *(const uint4*)(gp0 + cgB + hh * 16);
                a1.v = *(const uint4*)(gp1 + cgB + hh * 16);
                a2.v = *(const uint4*)(gp2 + cgB + hh * 16);
#pragma unroll
                for (int i = 0; i < 8; ++i)
                    ov.s[i] = f2b(gw0 * b2f(a0.s[i]) + gw1 * b2f(a1.s[i]) + gw2 * b2f(a2.s[i]));
                *(uint4*)(gdst + (((t & 3) * 32 + hh * 16) ^ gsw)) = ov.v;
            }
        }
#pragma unroll
        for (int q = 0; q < 4; ++q) {
            int o = q * 64 + (t >> 3);
            int bco = (sub * 16) ^ ((o & 7) << 4);
            const char* src = (const char*)w0b + (((size_t)o) * CIN + k0) * 2 + bco;
            char* dst = (char*)BlsP + (q * 512 + wv * 64) * 16;
            GLD16(src, dst);
        }
        __syncthreads();
#pragma unroll
        for (int kk = 0; kk < 2; ++kk) {
            short8 af[4], bfr[4];
#pragma unroll
            for (int fm = 0; fm < 4; ++fm) {
                int row = wm * 64 + fm * 16 + lc;
                int bcol = kk * 64 + g * 16;
                af[fm] = *(const short8*)(AlsP + row * 128 + (bcol ^ ((row & 7) << 4)));
            }
#pragma unroll
            for (int fn = 0; fn < 4; ++fn) {
                int o = wn * 64 + fn * 16 + lc;
                int bcol = kk * 64 + g * 16;
                bfr[fn] = *(const short8*)((const char*)BlsP + o * 128 + (bcol ^ ((o & 7) << 4)));
            }
#pragma unroll
            for (int fm = 0; fm < 4; ++fm)
#pragma unroll
                for (int fn = 0; fn < 4; ++fn)
                    acc[fm][fn] = __builtin_amdgcn_mfma_f32_16x16x32_bf16(af[fm], bfr[fn], acc[fm][fn], 0, 0, 0);
        }
    }

    // BN1 per-block partials from registers
    {
        float s1[4] = {0,0,0,0}, s2v[4] = {0,0,0,0};
#pragma unroll
        for (int fm = 0; fm < 4; ++fm)
#pragma unroll
            for (int fn = 0; fn < 4; ++fn)
#pragma unroll
                for (int j = 0; j < 4; ++j) {
                    float v = acc[fm][fn][j];
                    s1[fn] += v; s2v[fn] += v * v;
                }
#pragma unroll
        for (int fn = 0; fn < 4; ++fn) {
            s1[fn] += __shfl_xor(s1[fn], 16); s1[fn] += __shfl_xor(s1[fn], 32);
            s2v[fn] += __shfl_xor(s2v[fn], 16); s2v[fn] += __shfl_xor(s2v[fn], 32);
        }
        __syncthreads();
        if (l < 16) {
#pragma unroll
            for (int fn = 0; fn < 4; ++fn) {
                lsumA[wm * 256 + wn * 64 + fn * 16 + l] = s1[fn];
                lsqA [wm * 256 + wn * 64 + fn * 16 + l] = s2v[fn];
            }
        }
        __syncthreads();
        if (t < 256) {
            ast(part1 + (size_t)t * NGRID + bid,          lsumA[t] + lsumA[256 + t]);
            ast(part1 + (size_t)(C0 + t) * NGRID + bid,   lsqA[t]  + lsqA[256 + t]);
        }
    }

    gridbar(bar + 0);

    // BN1 stats: block ch<256 reduces its channel across 512 blocks
    if (bid < C0) {
        float s = ald(part1 + (size_t)bid * NGRID + t);
        float q = ald(part1 + (size_t)(C0 + bid) * NGRID + t);
#pragma unroll
        for (int r = 1; r <= 32; r <<= 1) { s += __shfl_xor(s, r); q += __shfl_xor(q, r); }
        float* red = (float*)lds;
        if (l == 0) { red[wv] = s; red[8 + wv] = q; }
        __syncthreads();
        if (t == 0) {
            float ss = 0.f, qq = 0.f;
#pragma unroll
            for (int i = 0; i < 8; ++i) { ss += red[i]; qq += red[8 + i]; }
            const float inv = 1.0f / (float)MM;
            float mean = ss * inv;
            float var = qq * inv - mean * mean;
            float scale = g0[bid] * rsqrtf(var + 1e-5f);
            ast(sc1 + bid, scale);
            ast(sh1 + bid, be0[bid] - mean * scale);
        }
    }

    gridbar(bar + 1);

    // BN1+ReLU -> h1tile (bf16, XOR-swizzled within 512B rows)
    {
        float scA[4], shA[4];
#pragma unroll
        for (int fn = 0; fn < 4; ++fn) {
            int col = wn * 64 + fn * 16 + lc;
            scA[fn] = ald(sc1 + col); shA[fn] = ald(sh1 + col);
        }
#pragma unroll
        for (int fm = 0; fm < 4; ++fm)
#pragma unroll
            for (int fn = 0; fn < 4; ++fn) {
                int col = wn * 64 + fn * 16 + lc;
#pragma unroll
                for (int j = 0; j < 4; ++j) {
                    int row = wm * 64 + fm * 16 + g * 4 + j;
                    float v = acc[fm][fn][j];
                    float h = fmaxf(0.0f, fmaf(scA[fn], v, shA[fn]));
                    *(unsigned short*)(lds + row * 512 + ((col * 2) ^ ((row & 7) << 4))) = f2b(h);
                }
            }
    }
    __syncthreads();

    // ----- phase 2: GEMM2 (A: h1tile LDS; B: w1b direct from global/L2) -----
    const int wm2 = wv >> 1, wn2 = wv & 1;
    f32x4 acc2[2][4];
#pragma unroll
    for (int i = 0; i < 2; ++i)
#pragma unroll
        for (int j = 0; j < 4; ++j) acc2[i][j] = (f32x4){0.f, 0.f, 0.f, 0.f};

#pragma unroll
    for (int ks2 = 0; ks2 < 4; ++ks2) {
#pragma unroll
        for (int kk = 0; kk < 2; ++kk) {
            const int bcol = ks2 * 128 + kk * 64 + g * 16;   // byte offset in 512B row
            short8 af2[2], bf2[4];
#pragma unroll
            for (int fm2 = 0; fm2 < 2; ++fm2) {
                int row = wm2 * 32 + fm2 * 16 + lc;
                af2[fm2] = *(const short8*)(lds + row * 512 + (bcol ^ ((row & 7) << 4)));
            }
#pragma unroll
            for (int fn2 = 0; fn2 < 4; ++fn2) {
                int o = wn2 * 64 + fn2 * 16 + lc;
                bf2[fn2] = *(const short8*)((const char*)w1b + (size_t)o * 512 + bcol);
            }
#pragma unroll
            for (int fm2 = 0; fm2 < 2; ++fm2)
#pragma unroll
                for (int fn2 = 0; fn2 < 4; ++fn2)
                    acc2[fm2][fn2] = __builtin_amdgcn_mfma_f32_16x16x32_bf16(af2[fm2], bf2[fn2], acc2[fm2][fn2], 0, 0, 0);
        }
    }

    // BN2 partials
    {
        float s1b[4] = {0,0,0,0}, s2b[4] = {0,0,0,0};
#pragma unroll
        for (int fm2 = 0; fm2 < 2; ++fm2)
#pragma unroll
            for (int fn2 = 0; fn2 < 4; ++fn2)
#pragma unroll
                for (int j = 0; j < 4; ++j) {
                    float v = acc2[fm2][fn2][j];
                    s1b[fn2] += v; s2b[fn2] += v * v;
                }
#pragma unroll
        for (int fn2 = 0; fn2 < 4; ++fn2) {
            s1b[fn2] += __shfl_xor(s1b[fn2], 16); s1b[fn2] += __shfl_xor(s1b[fn2], 32);
            s2b[fn2] += __shfl_xor(s2b[fn2], 16); s2b[fn2] += __shfl_xor(s2b[fn2], 32);
        }
        __syncthreads();                      // h1tile dead; reuse lds@0
        float* pst = (float*)lds;             // [4][128] sums, [4][128] sqs
        if (l < 16) {
#pragma unroll
            for (int fn2 = 0; fn2 < 4; ++fn2) {
                pst[wm2 * 128 + wn2 * 64 + fn2 * 16 + l]       = s1b[fn2];
                pst[512 + wm2 * 128 + wn2 * 64 + fn2 * 16 + l] = s2b[fn2];
            }
        }
        __syncthreads();
        if (t < C1) {
            float ssum = pst[t] + pst[128 + t] + pst[256 + t] + pst[384 + t];
            float sq   = pst[512 + t] + pst[640 + t] + pst[768 + t] + pst[896 + t];
            ast(part2g + (size_t)t * NGRID + bid,        ssum);
            ast(part2g + (size_t)(C1 + t) * NGRID + bid, sq);
        }
    }

    gridbar(bar + 2);

    // BN2 stats
    if (bid < C1) {
        float s = ald(part2g + (size_t)bid * NGRID + t);
        float q = ald(part2g + (size_t)(C1 + bid) * NGRID + t);
#pragma unroll
        for (int r = 1; r <= 32; r <<= 1) { s += __shfl_xor(s, r); q += __shfl_xor(q, r); }
        float* red = (float*)lds;
        if (l == 0) { red[wv] = s; red[8 + wv] = q; }
        __syncthreads();
        if (t == 0) {
            float ss = 0.f, qq = 0.f;
#pragma unroll
            for (int i = 0; i < 8; ++i) { ss += red[i]; qq += red[8 + i]; }
            const float inv = 1.0f / (float)MM;
            float mean = ss * inv;
            float var = qq * inv - mean * mean;
            float scale = g1[bid] * rsqrtf(var + 1e-5f);
            ast(sc2 + bid, scale);
            ast(sh2 + bid, be1[bid] - mean * scale);
        }
    }

    gridbar(bar + 3);

    // BN2+ReLU -> LDS transpose -> coalesced f32 out [b, o, n]
    {
        float sc2A[4], sh2A[4];
#pragma unroll
        for (int fn2 = 0; fn2 < 4; ++fn2) {
            int col = wn2 * 64 + fn2 * 16 + lc;
            sc2A[fn2] = ald(sc2 + col); sh2A[fn2] = ald(sh2 + col);
        }
        __syncthreads();
        float* trs = (float*)lds;             // [128][129]
#pragma unroll
        for (int fm2 = 0; fm2 < 2; ++fm2)
#pragma unroll
            for (int fn2 = 0; fn2 < 4; ++fn2) {
                int col = wn2 * 64 + fn2 * 16 + lc;
#pragma unroll
                for (int j = 0; j < 4; ++j) {
                    int rowl = wm2 * 32 + fm2 * 16 + g * 4 + j;
                    float h = fmaxf(0.0f, fmaf(sc2A[fn2], acc2[fm2][fn2][j], sh2A[fn2]));
                    trs[rowl * 129 + col] = h;
                }
            }
        __syncthreads();
        const int n0 = (bid & 31) * 128;
        const int nn = t & 127;
#pragma unroll
        for (int oo = t >> 7; oo < C1; oo += 4)
            out[((size_t)(b * C1 + oo)) * NN + n0 + nn] = trs[nn * 129 + oo];
    }
}

// ---------- launch ----------
extern "C" void kernel_launch(void* const* d_in, const int* in_sizes, int n_in,
                              void* d_out, int out_size, void* d_ws, size_t ws_size,
                              hipStream_t stream)
{
    const float* xyz1    = (const float*)d_in[0];
    const float* xyz2    = (const float*)d_in[1];
    const float* points1 = (const float*)d_in[2];
    const float* points2 = (const float*)d_in[3];
    const float* w0      = (const float*)d_in[4];
    const float* g0      = (const float*)d_in[6];
    const float* be0     = (const float*)d_in[7];
    const float* w1      = (const float*)d_in[8];
    const float* g1      = (const float*)d_in[10];
    const float* be1     = (const float*)d_in[11];
    float* out = (float*)d_out;
    char* ws = (char*)d_ws;

    unsigned short* P1T = (unsigned short*)(ws + 0);           // 16777216
    unsigned short* P2T = (unsigned short*)(ws + 16777216);    // 8388608
    double* trip = (double*)(ws + 25165824);                   // 3145728
    float* wtb   = (float*)(ws + 28311552);                    // 786432
    unsigned short* w0b = (unsigned short*)(ws + 29097984);    // 196608
    unsigned short* w1b = (unsigned short*)(ws + 29294592);    // 65536
    float* part1 = (float*)(ws + 29360128);                    // 2*256*512*4 = 1048576
    float* part2g= (float*)(ws + 30408704);                    // 2*128*512*4 = 524288
    float* sc1   = (float*)(ws + 30932992);
    float* sh1   = (float*)(ws + 30934016);
    float* sc2   = (float*)(ws + 30935040);
    float* sh2   = (float*)(ws + 30935552);
    unsigned* bar= (unsigned*)(ws + 30936064);                 // 64 B
    // total ws needed: ~31 MB

    hipMemsetAsync((void*)bar, 0, 64, stream);
    mega_front_k<<<118 * 64, 256, 0, stream>>>(xyz1, xyz2, points1, points2, w0, w1,
                                               P1T, P2T, w0b, w1b, trip, wtb);
    fused_mid_k<<<NGRID, 512, 0, stream>>>(P1T, P2T, trip, wtb, w0b, w1b,
                                           g0, be0, g1, be1, part1, part2g,
                                           sc1, sh1, sc2, sh2, bar, out);
}

// Round 12
// 126.398 us; speedup vs baseline: 4.3458x; 4.3458x over previous
//
#include <hip/hip_runtime.h>
#include <cstdint>
#include <cstddef>

// ---------- problem constants ----------
#define BB   16
#define NN   4096
#define SS   1024
#define D1   128
#define D2   256
#define CIN  384
#define C0   256
#define C1   128
#define MM   (BB*NN)          // 65536
#define NBLK (MM/128)         // 512 gemm blocks

typedef __attribute__((ext_vector_type(8))) short short8;
typedef __attribute__((ext_vector_type(4))) float f32x4;

__device__ __forceinline__ float b2f(unsigned short h) {
    union { unsigned int u; float f; } x; x.u = ((unsigned int)h) << 16; return x.f;
}
__device__ __forceinline__ unsigned short f2b(float f) {
    union { float f; unsigned int u; } x; x.f = f;
    unsigned int r = x.u + 0x7FFFu + ((x.u >> 16) & 1u);
    return (unsigned short)(r >> 16);
}

#define GLD16(g, l) __builtin_amdgcn_global_load_lds( \
    (const __attribute__((address_space(1))) void*)(g), \
    (__attribute__((address_space(3))) void*)(l), 16, 0, 0)

// ---------- knn v7: half-candidate blocks (512 cands each), f64 packed keys ----------
__device__ __forceinline__ void knn_body7(const float* __restrict__ xyz1,
                                          const float* __restrict__ xyz2,
                                          double* __restrict__ trip, float* __restrict__ wtb,
                                          int kb, int t, char* smem)
{
    float4* cnd = (float4*)smem;           // [8][65] float4, chunk-padded
    const int h    = kb & 1;
    const int pb   = kb >> 1;
    const int b    = pb >> 7;
    const int bx   = pb & 127;
    const int chunk = t & 7;
    const int n    = bx * 32 + (t >> 3);

    for (int i = t; i < 512; i += 256) {
        int s = h * 512 + i;
        float qx = xyz2[((size_t)b * 3 + 0) * SS + s];
        float qy = xyz2[((size_t)b * 3 + 1) * SS + s];
        float qz = xyz2[((size_t)b * 3 + 2) * SS + s];
        cnd[(i >> 6) * 65 + (i & 63)] = make_float4(qx, qy, qz, 0.f);
    }
    __syncthreads();

    const float px = xyz1[((size_t)b * 3 + 0) * NN + n];
    const float py = xyz1[((size_t)b * 3 + 1) * NN + n];
    const float pz = xyz1[((size_t)b * 3 + 2) * NN + n];

    const double INITK = __hiloint2double(0x7F7FFFFF, 0);
    double A0 = INITK, A1 = INITK, A2 = INITK;
    double B0 = INITK, B1 = INITK, B2 = INITK;
    const float4* cc = cnd + chunk * 65;
    const int sbase = h * 512 + chunk * 64;

#pragma unroll 4
    for (int c = 0; c < 64; c += 2) {
        {
            float4 q = cc[c];
            float dx = px - q.x, dy = py - q.y, dz = pz - q.z;
            float d = dx*dx + dy*dy + dz*dz;
            double k = __hiloint2double(__float_as_int(d), sbase + c);
            double t0 = fmin(k, A0), h0 = fmax(k, A0);
            double t1 = fmin(h0, A1), h1 = fmax(h0, A1);
            A2 = fmin(h1, A2); A0 = t0; A1 = t1;
        }
        {
            float4 q = cc[c + 1];
            float dx = px - q.x, dy = py - q.y, dz = pz - q.z;
            float d = dx*dx + dy*dy + dz*dz;
            double k = __hiloint2double(__float_as_int(d), sbase + c + 1);
            double t0 = fmin(k, B0), h0 = fmax(k, B0);
            double t1 = fmin(h0, B1), h1 = fmax(h0, B1);
            B2 = fmin(h1, B2); B0 = t0; B1 = t1;
        }
    }

    double K0, K1, K2;
    {
        double y0 = fmax(A0, B0);
        K0 = fmin(A0, B0);
        double x1 = fmin(A1, B1);
        K1 = fmin(y0, x1);
        double z  = fmax(y0, x1);
        K2 = fmin(z, fmin(A2, B2));
    }
#pragma unroll
    for (int r = 1; r <= 4; r <<= 1) {
        double C0d = __shfl_xor(K0, r);
        double C1d = __shfl_xor(K1, r);
        double C2d = __shfl_xor(K2, r);
        double y0 = fmax(K0, C0d);
        K0 = fmin(K0, C0d);
        double x1 = fmin(K1, C1d);
        double nK1 = fmin(y0, x1);
        double z  = fmax(y0, x1);
        K2 = fmin(z, fmin(K2, C2d));
        K1 = nK1;
    }

    if (chunk == 0) {
        size_t m = (size_t)b * NN + n;
        double* tp = trip + ((size_t)h * MM + m) * 3;
        tp[0] = K0; tp[1] = K1; tp[2] = K2;
        if (h == 0) {
            float4 q0 = cnd[0], q1 = cnd[1], q2 = cnd[2];
            float dd0, dd1, dd2;
            { float dx=px-q0.x, dy=py-q0.y, dz=pz-q0.z; dd0 = fmaxf(dx*dx+dy*dy+dz*dz, 1e-10f); }
            { float dx=px-q1.x, dy=py-q1.y, dz=pz-q1.z; dd1 = fmaxf(dx*dx+dy*dy+dz*dz, 1e-10f); }
            { float dx=px-q2.x, dy=py-q2.y, dz=pz-q2.z; dd2 = fmaxf(dx*dx+dy*dy+dz*dz, 1e-10f); }
            float r0 = 1.f/dd0, r1 = 1.f/dd1, r2 = 1.f/dd2;
            float inv = 1.f / (r0 + r1 + r2);
            wtb[m*3+0] = r0*inv; wtb[m*3+1] = r1*inv; wtb[m*3+2] = r2*inv;
        }
    }
}

__device__ __forceinline__ void transpose_body(const float* __restrict__ src,
                                               unsigned short* __restrict__ dst,
                                               int C, int Np, int dstStride,
                                               int b, int cblk, int nblk, int t, char* smem)
{
    float (*tile)[65] = (float(*)[65])smem;
    const int c0 = cblk * 64, n0 = nblk * 64;
    const int j = t & 63, i4 = t >> 6;
#pragma unroll
    for (int p = 0; p < 64; p += 4) {
        int ci = p + i4;
        tile[ci][j] = src[((size_t)b * C + c0 + ci) * Np + n0 + j];
    }
    __syncthreads();
#pragma unroll
    for (int p = 0; p < 64; p += 4) {
        int ni = p + i4;
        dst[((size_t)b * Np + n0 + ni) * dstStride + c0 + j] = f2b(tile[j][ni]);
    }
}

// ---------- mega front: knn halves + transposes + weight cvt ----------
__global__ __launch_bounds__(256) void mega_front_k(
    const float* __restrict__ xyz1, const float* __restrict__ xyz2,
    const float* __restrict__ points1, const float* __restrict__ points2,
    const float* __restrict__ w0, const float* __restrict__ w1,
    unsigned short* __restrict__ P1T, unsigned short* __restrict__ P2T,
    unsigned short* __restrict__ w0b, unsigned short* __restrict__ w1b,
    double* __restrict__ trip, float* __restrict__ wtb)
{
    __shared__ __align__(16) char smem[16640];
    const unsigned bid = blockIdx.x;
    const int g = bid / 118, r = bid % 118;
    const int t = threadIdx.x;

    if (r < 64) {
        knn_body7(xyz1, xyz2, trip, wtb, g * 64 + r, t, smem);
    } else if (r < 96) {
        int rb = g * 32 + (r - 64);
        transpose_body(points1, P1T, D1, NN, D1,
                       rb >> 7, (rb >> 6) & 1, rb & 63, t, smem);
    } else if (r < 112) {
        int rb = g * 16 + (r - 96);
        transpose_body(points2, P2T, D2, SS, D2,
                       rb >> 6, (rb >> 4) & 3, rb & 15, t, smem);
    } else {
        int rb = g * 6 + (r - 112);
        int i = rb * 256 + t;
        if (i < C0 * CIN) w0b[i] = f2b(w0[i]);
        if (i < C1 * C0)  w1b[i] = f2b(w1[i]);
    }
}

// ---------- K3: GEMM1; interp fused into A staging, gathers prefetched 1 K-step ahead ----------
__launch_bounds__(512, 4)
__global__ void gemm1_k(const unsigned short* __restrict__ P1T,
                        const unsigned short* __restrict__ P2T,
                        const double* __restrict__ trip, const float* __restrict__ wtb,
                        const unsigned short* __restrict__ w0b,
                        unsigned short* __restrict__ h1, float* __restrict__ part1)
{
    __shared__ unsigned short Als[128 * 64];   // [row][k] bf16, XOR-swizzled
    __shared__ unsigned short Bls[256 * 64];
    __shared__ float lsum[2][256];
    __shared__ float lsq[2][256];

    const int t = threadIdx.x;
    const int wv = t >> 6, l = t & 63, g = l >> 4, lc = l & 15;
    const int wm = wv >> 2, wn = wv & 3;
    const int m0 = blockIdx.x * 128;
    const int b  = blockIdx.x >> 5;            // 32 blocks per batch
    const int sub = t & 7;

    const int grow = t >> 2;
    const size_t gm = (size_t)(m0 + grow);
    // merge the two knn half-triples (exact f64 merge, keys unique)
    const double* tpA = trip + gm * 3;
    const double* tpB = trip + ((size_t)MM + gm) * 3;
    double hA0 = tpA[0], hA1 = tpA[1], hA2 = tpA[2];
    double hB0 = tpB[0], hB1 = tpB[1], hB2 = tpB[2];
    double y0 = fmax(hA0, hB0), K0 = fmin(hA0, hB0);
    double x1 = fmin(hA1, hB1), K1 = fmin(y0, x1);
    double z  = fmax(y0, x1),   K2 = fmin(z, fmin(hA2, hB2));
    const int gi0 = __double2loint(K0);
    const int gi1 = __double2loint(K1);
    const int gi2 = __double2loint(K2);
    const float gw0 = wtb[gm*3], gw1 = wtb[gm*3+1], gw2 = wtb[gm*3+2];
    const char* gp0 = (const char*)(P2T + ((size_t)b * SS + gi0) * D2) + (t & 3) * 32;
    const char* gp1 = (const char*)(P2T + ((size_t)b * SS + gi1) * D2) + (t & 3) * 32;
    const char* gp2 = (const char*)(P2T + ((size_t)b * SS + gi2) * D2) + (t & 3) * 32;
    char* gdst = (char*)Als + grow * 128;
    const int gsw = (grow & 7) << 4;

    // prefetch gathers for the first interp step (ks=2, cgB=0)
    uint4 pa0[2], pa1[2], pa2[2];
    pa0[0] = *(const uint4*)(gp0);      pa0[1] = *(const uint4*)(gp0 + 16);
    pa1[0] = *(const uint4*)(gp1);      pa1[1] = *(const uint4*)(gp1 + 16);
    pa2[0] = *(const uint4*)(gp2);      pa2[1] = *(const uint4*)(gp2 + 16);

    f32x4 acc[4][4];
#pragma unroll
    for (int i = 0; i < 4; ++i)
#pragma unroll
        for (int j = 0; j < 4; ++j) acc[i][j] = (f32x4){0.f, 0.f, 0.f, 0.f};

    for (int ks = 0; ks < 6; ++ks) {
        const int k0 = ks * 64;
        __syncthreads();
        if (ks < 2) {
#pragma unroll
            for (int q = 0; q < 2; ++q) {
                int row = q * 64 + (t >> 3);
                int bco = (sub * 16) ^ ((row & 7) << 4);
                const char* src = (const char*)P1T + (((size_t)(m0 + row)) * D1 + k0) * 2 + bco;
                char* dst = (char*)Als + (q * 512 + wv * 64) * 16;
                GLD16(src, dst);
            }
        } else {
            // convert prefetched gathers -> Als (swizzled)
#pragma unroll
            for (int h = 0; h < 2; ++h) {
                union { uint4 v; unsigned short s[8]; } a0, a1, a2, ov;
                a0.v = pa0[h]; a1.v = pa1[h]; a2.v = pa2[h];
#pragma unroll
                for (int i = 0; i < 8; ++i)
                    ov.s[i] = f2b(gw0 * b2f(a0.s[i]) + gw1 * b2f(a1.s[i]) + gw2 * b2f(a2.s[i]));
                *(uint4*)(gdst + (((t & 3) * 32 + h * 16) ^ gsw)) = ov.v;
            }
            // issue next step's gathers; latency hides under this step's MFMA
            if (ks < 5) {
                const int ncgB = (ks - 1) * 128;
                pa0[0] = *(const uint4*)(gp0 + ncgB);  pa0[1] = *(const uint4*)(gp0 + ncgB + 16);
                pa1[0] = *(const uint4*)(gp1 + ncgB);  pa1[1] = *(const uint4*)(gp1 + ncgB + 16);
                pa2[0] = *(const uint4*)(gp2 + ncgB);  pa2[1] = *(const uint4*)(gp2 + ncgB + 16);
            }
        }
#pragma unroll
        for (int q = 0; q < 4; ++q) {      // B: 32KB
            int o = q * 64 + (t >> 3);
            int bco = (sub * 16) ^ ((o & 7) << 4);
            const char* src = (const char*)w0b + (((size_t)o) * CIN + k0) * 2 + bco;
            char* dst = (char*)Bls + (q * 512 + wv * 64) * 16;
            GLD16(src, dst);
        }
        __syncthreads();
#pragma unroll
        for (int kk = 0; kk < 2; ++kk) {
            short8 af[4], bfr[4];
#pragma unroll
            for (int fm = 0; fm < 4; ++fm) {
                int row = wm * 64 + fm * 16 + lc;
                int bcol = kk * 64 + g * 16;
                af[fm] = *(const short8*)((const char*)Als + row * 128 + (bcol ^ ((row & 7) << 4)));
            }
#pragma unroll
            for (int fn = 0; fn < 4; ++fn) {
                int o = wn * 64 + fn * 16 + lc;
                int bcol = kk * 64 + g * 16;
                bfr[fn] = *(const short8*)((const char*)Bls + o * 128 + (bcol ^ ((o & 7) << 4)));
            }
#pragma unroll
            for (int fm = 0; fm < 4; ++fm)
#pragma unroll
                for (int fn = 0; fn < 4; ++fn)
                    acc[fm][fn] = __builtin_amdgcn_mfma_f32_16x16x32_bf16(af[fm], bfr[fn], acc[fm][fn], 0, 0, 0);
        }
    }

    float s1[4] = {0,0,0,0}, s2v[4] = {0,0,0,0};
#pragma unroll
    for (int fm = 0; fm < 4; ++fm)
#pragma unroll
        for (int fn = 0; fn < 4; ++fn) {
            int row = m0 + wm * 64 + fm * 16 + g * 4;
            int col = wn * 64 + fn * 16 + lc;
#pragma unroll
            for (int j = 0; j < 4; ++j) {
                float v = acc[fm][fn][j];
                h1[((size_t)(row + j)) * C0 + col] = f2b(v);
                s1[fn] += v; s2v[fn] += v * v;
            }
        }
#pragma unroll
    for (int fn = 0; fn < 4; ++fn) {
        s1[fn] += __shfl_xor(s1[fn], 16); s1[fn] += __shfl_xor(s1[fn], 32);
        s2v[fn] += __shfl_xor(s2v[fn], 16); s2v[fn] += __shfl_xor(s2v[fn], 32);
    }
    if (l < 16) {
#pragma unroll
        for (int fn = 0; fn < 4; ++fn) {
            lsum[wm][wn * 64 + fn * 16 + l] = s1[fn];
            lsq[wm][wn * 64 + fn * 16 + l] = s2v[fn];
        }
    }
    __syncthreads();
    if (t < 256) {
        part1[(size_t)t * NBLK + blockIdx.x]        = lsum[0][t] + lsum[1][t];
        part1[(size_t)(C0 + t) * NBLK + blockIdx.x] = lsq[0][t] + lsq[1][t];
    }
}

// ---------- stats: one wave per channel, coalesced [channel][block] reads ----------
__global__ void stats_k(const float* __restrict__ part, int nblk, int C,
                        const float* __restrict__ gam, const float* __restrict__ bet,
                        float* __restrict__ sc, float* __restrict__ sh)
{
    const int w = threadIdx.x >> 6, l = threadIdx.x & 63;
    const int o = blockIdx.x * 4 + w;
    if (o >= C) return;
    float s = 0.f, q = 0.f;
    for (int i = l; i < nblk; i += 64) {
        s += part[(size_t)o * nblk + i];
        q += part[(size_t)(C + o) * nblk + i];
    }
#pragma unroll
    for (int r = 32; r; r >>= 1) { s += __shfl_xor(s, r); q += __shfl_xor(q, r); }
    if (l == 0) {
        const float inv = 1.0f / (float)MM;
        float mean = s * inv;
        float var = q * inv - mean * mean;
        float scale = gam[o] * rsqrtf(var + 1e-5f);
        sc[o] = scale;
        sh[o] = bet[o] - mean * scale;
    }
}

// ---------- K5: GEMM2 with BN1+ReLU fused into A staging; h1 loads prefetched ----------
__launch_bounds__(256, 4)
__global__ void gemm2_k(const unsigned short* __restrict__ h1, const unsigned short* __restrict__ w1b,
                        const float* __restrict__ sc1, const float* __restrict__ sh1,
                        unsigned short* __restrict__ h2, float* __restrict__ part2)
{
    __shared__ unsigned short Als[128 * 64];
    __shared__ unsigned short Bls[128 * 64];
    __shared__ float scl[256], shl[256];
    __shared__ float lsum[2][128];
    __shared__ float lsq[2][128];

    const int t = threadIdx.x;
    const int wv = t >> 6, l = t & 63, g = l >> 4, lc = l & 15;
    const int wm = wv >> 1, wn = wv & 1;
    const int m0 = blockIdx.x * 128;
    const int sub = t & 7;

    scl[t] = sc1[t]; shl[t] = sh1[t];

    // prefetch A rows for ks=0
    uint4 r[4];
#pragma unroll
    for (int q = 0; q < 4; ++q) {
        int row = q * 32 + (t >> 3);
        r[q] = *(const uint4*)((const char*)h1 + (((size_t)(m0 + row)) * C0) * 2 + sub * 16);
    }

    f32x4 acc[4][4];
#pragma unroll
    for (int i = 0; i < 4; ++i)
#pragma unroll
        for (int j = 0; j < 4; ++j) acc[i][j] = (f32x4){0.f, 0.f, 0.f, 0.f};

    for (int ks = 0; ks < 4; ++ks) {
        const int k0 = ks * 64;
        __syncthreads();
#pragma unroll
        for (int q = 0; q < 4; ++q) {
            int row = q * 32 + (t >> 3);
            union { uint4 v; unsigned short s[8]; } u, ov;
            u.v = r[q];
#pragma unroll
            for (int i = 0; i < 8; ++i) {
                int k = k0 + sub * 8 + i;
                float f = b2f(u.s[i]);
                ov.s[i] = f2b(fmaxf(0.0f, fmaf(scl[k], f, shl[k])));
            }
            *(uint4*)((char*)Als + row * 128 + ((sub * 16) ^ ((row & 7) << 4))) = ov.v;
        }
#pragma unroll
        for (int q = 0; q < 4; ++q) {
            int o = q * 32 + (t >> 3);
            int bco = (sub * 16) ^ ((o & 7) << 4);
            const char* src = (const char*)w1b + (((size_t)o) * C0 + k0) * 2 + bco;
            char* dst = (char*)Bls + (q * 256 + wv * 64) * 16;
            GLD16(src, dst);
        }
        // issue next step's h1 loads; latency hides under this step's MFMA
        if (ks < 3) {
#pragma unroll
            for (int q = 0; q < 4; ++q) {
                int row = q * 32 + (t >> 3);
                r[q] = *(const uint4*)((const char*)h1 + (((size_t)(m0 + row)) * C0 + k0 + 64) * 2 + sub * 16);
            }
        }
        __syncthreads();
#pragma unroll
        for (int kk = 0; kk < 2; ++kk) {
            short8 af[4], bfr[4];
#pragma unroll
            for (int fm = 0; fm < 4; ++fm) {
                int row = wm * 64 + fm * 16 + lc;
                int bcol = kk * 64 + g * 16;
                af[fm] = *(const short8*)((const char*)Als + row * 128 + (bcol ^ ((row & 7) << 4)));
            }
#pragma unroll
            for (int fn = 0; fn < 4; ++fn) {
                int o = wn * 64 + fn * 16 + lc;
                int bcol = kk * 64 + g * 16;
                bfr[fn] = *(const short8*)((const char*)Bls + o * 128 + (bcol ^ ((o & 7) << 4)));
            }
#pragma unroll
            for (int fm = 0; fm < 4; ++fm)
#pragma unroll
                for (int fn = 0; fn < 4; ++fn)
                    acc[fm][fn] = __builtin_amdgcn_mfma_f32_16x16x32_bf16(af[fm], bfr[fn], acc[fm][fn], 0, 0, 0);
        }
    }

    float s1[4] = {0,0,0,0}, s2v[4] = {0,0,0,0};
#pragma unroll
    for (int fm = 0; fm < 4; ++fm)
#pragma unroll
        for (int fn = 0; fn < 4; ++fn) {
            int row = m0 + wm * 64 + fm * 16 + g * 4;
            int col = wn * 64 + fn * 16 + lc;
#pragma unroll
            for (int j = 0; j < 4; ++j) {
                float v = acc[fm][fn][j];
                h2[((size_t)(row + j)) * C1 + col] = f2b(v);
                s1[fn] += v; s2v[fn] += v * v;
            }
        }
#pragma unroll
    for (int fn = 0; fn < 4; ++fn) {
        s1[fn] += __shfl_xor(s1[fn], 16); s1[fn] += __shfl_xor(s1[fn], 32);
        s2v[fn] += __shfl_xor(s2v[fn], 16); s2v[fn] += __shfl_xor(s2v[fn], 32);
    }
    if (l < 16) {
#pragma unroll
        for (int fn = 0; fn < 4; ++fn) {
            lsum[wm][wn * 64 + fn * 16 + l] = s1[fn];
            lsq[wm][wn * 64 + fn * 16 + l] = s2v[fn];
        }
    }
    __syncthreads();
    if (t < 128) {
        part2[(size_t)t * NBLK + blockIdx.x]        = lsum[0][t] + lsum[1][t];
        part2[(size_t)(C1 + t) * NBLK + blockIdx.x] = lsq[0][t] + lsq[1][t];
    }
}

// ---------- K7: final BN2+ReLU + transpose [b,n,o] -> [b,o,n] f32 ----------
__global__ void finalize_k(const unsigned short* __restrict__ h2,
                           const float* __restrict__ sc, const float* __restrict__ sh,
                           float* __restrict__ out)
{
    __shared__ float tile[64][65];
    const int b = blockIdx.z, o0 = blockIdx.y * 64, n0 = blockIdx.x * 64;
    const int t = threadIdx.x, j = t & 63, i4 = t >> 6;
    const float scv = sc[o0 + j], shv = sh[o0 + j];
#pragma unroll
    for (int p = 0; p < 64; p += 4) {
        int ni = p + i4;
        float f = b2f(h2[((size_t)b * NN + n0 + ni) * C1 + o0 + j]);
        tile[ni][j] = fmaxf(0.0f, fmaf(scv, f, shv));
    }
    __syncthreads();
#pragma unroll
    for (int p = 0; p < 64; p += 4) {
        int oi = p + i4;
        out[((size_t)(b * C1 + o0 + oi)) * NN + n0 + j] = tile[j][oi];
    }
}

// ---------- launch ----------
extern "C" void kernel_launch(void* const* d_in, const int* in_sizes, int n_in,
                              void* d_out, int out_size, void* d_ws, size_t ws_size,
                              hipStream_t stream)
{
    const float* xyz1    = (const float*)d_in[0];
    const float* xyz2    = (const float*)d_in[1];
    const float* points1 = (const float*)d_in[2];
    const float* points2 = (const float*)d_in[3];
    const float* w0      = (const float*)d_in[4];
    const float* g0      = (const float*)d_in[6];
    const float* be0     = (const float*)d_in[7];
    const float* w1      = (const float*)d_in[8];
    const float* g1      = (const float*)d_in[10];
    const float* be1     = (const float*)d_in[11];
    float* out = (float*)d_out;
    char* ws = (char*)d_ws;

    unsigned short* P1T = (unsigned short*)(ws + 0);           // 16777216
    unsigned short* h1  = (unsigned short*)(ws + 16777216);    // 33554432
    unsigned short* P2T = (unsigned short*)(ws + 50331648);    // 8388608
    unsigned short* h2  = (unsigned short*)(ws + 58720256);    // 16777216
    double* trip = (double*)(ws + 75497472);                   // 3145728
    float* wtb   = (float*)(ws + 78643200);                    // 786432
    unsigned short* w0b = (unsigned short*)(ws + 79429632);    // 196608
    unsigned short* w1b = (unsigned short*)(ws + 79626240);    // 65536
    float* part1 = (float*)(ws + 79691776);                    // 1048576
    float* part2 = (float*)(ws + 80740352);                    // 524288
    float* sc1   = (float*)(ws + 81264640);
    float* sh1   = (float*)(ws + 81265664);
    float* sc2   = (float*)(ws + 81266688);
    float* sh2   = (float*)(ws + 81267712);
    // total ws needed: ~81.3 MB

    mega_front_k<<<118 * 64, 256, 0, stream>>>(xyz1, xyz2, points1, points2, w0, w1,
                                               P1T, P2T, w0b, w1b, trip, wtb);
    gemm1_k<<<MM/128, 512, 0, stream>>>(P1T, P2T, trip, wtb, w0b, h1, part1);
    stats_k<<<C0/4, 256, 0, stream>>>(part1, NBLK, C0, g0, be0, sc1, sh1);
    gemm2_k<<<MM/128, 256, 0, stream>>>(h1, w1b, sc1, sh1, h2, part2);
    stats_k<<<C1/4, 256, 0, stream>>>(part2, NBLK, C1, g1, be1, sc2, sh2);
    finalize_k<<<dim3(NN/64, C1/64, BB), 256, 0, stream>>>(h2, sc2, sh2, out);
}

// Round 13
// 105.528 us; speedup vs baseline: 5.2052x; 1.1978x over previous
//
#include <hip/hip_runtime.h>
#include <cstdint>
#include <cstddef>

// ---------- problem constants ----------
#define BB   16
#define NN   4096
#define SS   1024
#define D1   128
#define D2   256
#define CIN  384
#define C0   256
#define C1   128
#define MM   (BB*NN)          // 65536
#define NBLK (MM/128)         // 512 gemm blocks

typedef __attribute__((ext_vector_type(8))) short short8;
typedef __attribute__((ext_vector_type(4))) float f32x4;

__device__ __forceinline__ float b2f(unsigned short h) {
    union { unsigned int u; float f; } x; x.u = ((unsigned int)h) << 16; return x.f;
}
__device__ __forceinline__ unsigned short f2b(float f) {
    union { float f; unsigned int u; } x; x.f = f;
    unsigned int r = x.u + 0x7FFFu + ((x.u >> 16) & 1u);
    return (unsigned short)(r >> 16);
}

#define GLD16(g, l) __builtin_amdgcn_global_load_lds( \
    (const __attribute__((address_space(1))) void*)(g), \
    (__attribute__((address_space(3))) void*)(l), 16, 0, 0)

// ---------- knn v7: half-candidate blocks (512 cands each), f64 packed keys ----------
__device__ __forceinline__ void knn_body7(const float* __restrict__ xyz1,
                                          const float* __restrict__ xyz2,
                                          double* __restrict__ trip, float* __restrict__ wtb,
                                          int kb, int t, char* smem)
{
    float4* cnd = (float4*)smem;           // [8][65] float4, chunk-padded
    const int h    = kb & 1;
    const int pb   = kb >> 1;
    const int b    = pb >> 7;
    const int bx   = pb & 127;
    const int chunk = t & 7;
    const int n    = bx * 32 + (t >> 3);

    for (int i = t; i < 512; i += 256) {
        int s = h * 512 + i;
        float qx = xyz2[((size_t)b * 3 + 0) * SS + s];
        float qy = xyz2[((size_t)b * 3 + 1) * SS + s];
        float qz = xyz2[((size_t)b * 3 + 2) * SS + s];
        cnd[(i >> 6) * 65 + (i & 63)] = make_float4(qx, qy, qz, 0.f);
    }
    __syncthreads();

    const float px = xyz1[((size_t)b * 3 + 0) * NN + n];
    const float py = xyz1[((size_t)b * 3 + 1) * NN + n];
    const float pz = xyz1[((size_t)b * 3 + 2) * NN + n];

    const double INITK = __hiloint2double(0x7F7FFFFF, 0);
    double A0 = INITK, A1 = INITK, A2 = INITK;
    double B0 = INITK, B1 = INITK, B2 = INITK;
    const float4* cc = cnd + chunk * 65;
    const int sbase = h * 512 + chunk * 64;

#pragma unroll 4
    for (int c = 0; c < 64; c += 2) {
        {
            float4 q = cc[c];
            float dx = px - q.x, dy = py - q.y, dz = pz - q.z;
            float d = dx*dx + dy*dy + dz*dz;
            double k = __hiloint2double(__float_as_int(d), sbase + c);
            double t0 = fmin(k, A0), h0 = fmax(k, A0);
            double t1 = fmin(h0, A1), h1 = fmax(h0, A1);
            A2 = fmin(h1, A2); A0 = t0; A1 = t1;
        }
        {
            float4 q = cc[c + 1];
            float dx = px - q.x, dy = py - q.y, dz = pz - q.z;
            float d = dx*dx + dy*dy + dz*dz;
            double k = __hiloint2double(__float_as_int(d), sbase + c + 1);
            double t0 = fmin(k, B0), h0 = fmax(k, B0);
            double t1 = fmin(h0, B1), h1 = fmax(h0, B1);
            B2 = fmin(h1, B2); B0 = t0; B1 = t1;
        }
    }

    double K0, K1, K2;
    {
        double y0 = fmax(A0, B0);
        K0 = fmin(A0, B0);
        double x1 = fmin(A1, B1);
        K1 = fmin(y0, x1);
        double z  = fmax(y0, x1);
        K2 = fmin(z, fmin(A2, B2));
    }
#pragma unroll
    for (int r = 1; r <= 4; r <<= 1) {
        double C0d = __shfl_xor(K0, r);
        double C1d = __shfl_xor(K1, r);
        double C2d = __shfl_xor(K2, r);
        double y0 = fmax(K0, C0d);
        K0 = fmin(K0, C0d);
        double x1 = fmin(K1, C1d);
        double nK1 = fmin(y0, x1);
        double z  = fmax(y0, x1);
        K2 = fmin(z, fmin(K2, C2d));
        K1 = nK1;
    }

    if (chunk == 0) {
        size_t m = (size_t)b * NN + n;
        double* tp = trip + ((size_t)h * MM + m) * 3;
        tp[0] = K0; tp[1] = K1; tp[2] = K2;
        if (h == 0) {
            float4 q0 = cnd[0], q1 = cnd[1], q2 = cnd[2];
            float dd0, dd1, dd2;
            { float dx=px-q0.x, dy=py-q0.y, dz=pz-q0.z; dd0 = fmaxf(dx*dx+dy*dy+dz*dz, 1e-10f); }
            { float dx=px-q1.x, dy=py-q1.y, dz=pz-q1.z; dd1 = fmaxf(dx*dx+dy*dy+dz*dz, 1e-10f); }
            { float dx=px-q2.x, dy=py-q2.y, dz=pz-q2.z; dd2 = fmaxf(dx*dx+dy*dy+dz*dz, 1e-10f); }
            float r0 = 1.f/dd0, r1 = 1.f/dd1, r2 = 1.f/dd2;
            float inv = 1.f / (r0 + r1 + r2);
            wtb[m*3+0] = r0*inv; wtb[m*3+1] = r1*inv; wtb[m*3+2] = r2*inv;
        }
    }
}

__device__ __forceinline__ void transpose_body(const float* __restrict__ src,
                                               unsigned short* __restrict__ dst,
                                               int C, int Np, int dstStride,
                                               int b, int cblk, int nblk, int t, char* smem)
{
    float (*tile)[65] = (float(*)[65])smem;
    const int c0 = cblk * 64, n0 = nblk * 64;
    const int j = t & 63, i4 = t >> 6;
#pragma unroll
    for (int p = 0; p < 64; p += 4) {
        int ci = p + i4;
        tile[ci][j] = src[((size_t)b * C + c0 + ci) * Np + n0 + j];
    }
    __syncthreads();
#pragma unroll
    for (int p = 0; p < 64; p += 4) {
        int ni = p + i4;
        dst[((size_t)b * Np + n0 + ni) * dstStride + c0 + j] = f2b(tile[j][ni]);
    }
}

// ---------- mega front: knn halves + transposes + weight cvt ----------
__global__ __launch_bounds__(256) void mega_front_k(
    const float* __restrict__ xyz1, const float* __restrict__ xyz2,
    const float* __restrict__ points1, const float* __restrict__ points2,
    const float* __restrict__ w0, const float* __restrict__ w1,
    unsigned short* __restrict__ P1T, unsigned short* __restrict__ P2T,
    unsigned short* __restrict__ w0b, unsigned short* __restrict__ w1b,
    double* __restrict__ trip, float* __restrict__ wtb)
{
    __shared__ __align__(16) char smem[16640];
    const unsigned bid = blockIdx.x;
    const int g = bid / 118, r = bid % 118;
    const int t = threadIdx.x;

    if (r < 64) {
        knn_body7(xyz1, xyz2, trip, wtb, g * 64 + r, t, smem);
    } else if (r < 96) {
        int rb = g * 32 + (r - 64);
        transpose_body(points1, P1T, D1, NN, D1,
                       rb >> 7, (rb >> 6) & 1, rb & 63, t, smem);
    } else if (r < 112) {
        int rb = g * 16 + (r - 96);
        transpose_body(points2, P2T, D2, SS, D2,
                       rb >> 6, (rb >> 4) & 3, rb & 15, t, smem);
    } else {
        int rb = g * 6 + (r - 112);
        int i = rb * 256 + t;
        if (i < C0 * CIN) w0b[i] = f2b(w0[i]);
        if (i < C1 * C0)  w1b[i] = f2b(w1[i]);
    }
}

// ---------- K3: GEMM1 with interpolation fused; merges knn halves in prologue ----------
// XCD-chunked swizzle: HW assigns blockIdx i -> XCD i%8; wgid = (i%8)*64 + i/8
// gives each XCD one contiguous 64-wgid chunk = 2 batches -> P2T gathers (512KB
// per batch) become XCD-L2-resident instead of spread over all 8 L2s.
__launch_bounds__(512, 4)
__global__ void gemm1_k(const unsigned short* __restrict__ P1T,
                        const unsigned short* __restrict__ P2T,
                        const double* __restrict__ trip, const float* __restrict__ wtb,
                        const unsigned short* __restrict__ w0b,
                        unsigned short* __restrict__ h1, float* __restrict__ part1)
{
    __shared__ unsigned short Als[128 * 64];   // [row][k] bf16, XOR-swizzled
    __shared__ unsigned short Bls[256 * 64];
    __shared__ float lsum[2][256];
    __shared__ float lsq[2][256];

    const int t = threadIdx.x;
    const int wgid = ((int)blockIdx.x % 8) * (NBLK / 8) + (int)blockIdx.x / 8;
    const int wv = t >> 6, l = t & 63, g = l >> 4, lc = l & 15;
    const int wm = wv >> 2, wn = wv & 3;
    const int m0 = wgid * 128;
    const int b  = wgid >> 5;                  // 32 blocks per batch
    const int sub = t & 7;

    const int grow = t >> 2;
    const size_t gm = (size_t)(m0 + grow);
    // merge the two knn half-triples (exact f64 merge, keys unique)
    const double* tpA = trip + gm * 3;
    const double* tpB = trip + ((size_t)MM + gm) * 3;
    double hA0 = tpA[0], hA1 = tpA[1], hA2 = tpA[2];
    double hB0 = tpB[0], hB1 = tpB[1], hB2 = tpB[2];
    double y0 = fmax(hA0, hB0), K0 = fmin(hA0, hB0);
    double x1 = fmin(hA1, hB1), K1 = fmin(y0, x1);
    double z  = fmax(y0, x1),   K2 = fmin(z, fmin(hA2, hB2));
    const int gi0 = __double2loint(K0);
    const int gi1 = __double2loint(K1);
    const int gi2 = __double2loint(K2);
    const float gw0 = wtb[gm*3], gw1 = wtb[gm*3+1], gw2 = wtb[gm*3+2];
    const char* gp0 = (const char*)(P2T + ((size_t)b * SS + gi0) * D2) + (t & 3) * 32;
    const char* gp1 = (const char*)(P2T + ((size_t)b * SS + gi1) * D2) + (t & 3) * 32;
    const char* gp2 = (const char*)(P2T + ((size_t)b * SS + gi2) * D2) + (t & 3) * 32;
    char* gdst = (char*)Als + grow * 128;
    const int gsw = (grow & 7) << 4;

    f32x4 acc[4][4];
#pragma unroll
    for (int i = 0; i < 4; ++i)
#pragma unroll
        for (int j = 0; j < 4; ++j) acc[i][j] = (f32x4){0.f, 0.f, 0.f, 0.f};

    for (int ks = 0; ks < 6; ++ks) {
        const int k0 = ks * 64;
        __syncthreads();
        if (ks < 2) {
#pragma unroll
            for (int q = 0; q < 2; ++q) {
                int row = q * 64 + (t >> 3);
                int bco = (sub * 16) ^ ((row & 7) << 4);
                const char* src = (const char*)P1T + (((size_t)(m0 + row)) * D1 + k0) * 2 + bco;
                char* dst = (char*)Als + (q * 512 + wv * 64) * 16;
                GLD16(src, dst);
            }
        } else {
            const int cgB = (ks - 2) * 128;
#pragma unroll
            for (int h = 0; h < 2; ++h) {
                union { uint4 v; unsigned short s[8]; } a0, a1, a2, ov;
                a0.v = *(const uint4*)(gp0 + cgB + h * 16);
                a1.v = *(const uint4*)(gp1 + cgB + h * 16);
                a2.v = *(const uint4*)(gp2 + cgB + h * 16);
#pragma unroll
                for (int i = 0; i < 8; ++i)
                    ov.s[i] = f2b(gw0 * b2f(a0.s[i]) + gw1 * b2f(a1.s[i]) + gw2 * b2f(a2.s[i]));
                *(uint4*)(gdst + (((t & 3) * 32 + h * 16) ^ gsw)) = ov.v;
            }
        }
#pragma unroll
        for (int q = 0; q < 4; ++q) {      // B: 32KB
            int o = q * 64 + (t >> 3);
            int bco = (sub * 16) ^ ((o & 7) << 4);
            const char* src = (const char*)w0b + (((size_t)o) * CIN + k0) * 2 + bco;
            char* dst = (char*)Bls + (q * 512 + wv * 64) * 16;
            GLD16(src, dst);
        }
        __syncthreads();
#pragma unroll
        for (int kk = 0; kk < 2; ++kk) {
            short8 af[4], bfr[4];
#pragma unroll
            for (int fm = 0; fm < 4; ++fm) {
                int row = wm * 64 + fm * 16 + lc;
                int bcol = kk * 64 + g * 16;
                af[fm] = *(const short8*)((const char*)Als + row * 128 + (bcol ^ ((row & 7) << 4)));
            }
#pragma unroll
            for (int fn = 0; fn < 4; ++fn) {
                int o = wn * 64 + fn * 16 + lc;
                int bcol = kk * 64 + g * 16;
                bfr[fn] = *(const short8*)((const char*)Bls + o * 128 + (bcol ^ ((o & 7) << 4)));
            }
#pragma unroll
            for (int fm = 0; fm < 4; ++fm)
#pragma unroll
                for (int fn = 0; fn < 4; ++fn)
                    acc[fm][fn] = __builtin_amdgcn_mfma_f32_16x16x32_bf16(af[fm], bfr[fn], acc[fm][fn], 0, 0, 0);
        }
    }

    float s1[4] = {0,0,0,0}, s2v[4] = {0,0,0,0};
#pragma unroll
    for (int fm = 0; fm < 4; ++fm)
#pragma unroll
        for (int fn = 0; fn < 4; ++fn) {
            int row = m0 + wm * 64 + fm * 16 + g * 4;
            int col = wn * 64 + fn * 16 + lc;
#pragma unroll
            for (int j = 0; j < 4; ++j) {
                float v = acc[fm][fn][j];
                h1[((size_t)(row + j)) * C0 + col] = f2b(v);
                s1[fn] += v; s2v[fn] += v * v;
            }
        }
#pragma unroll
    for (int fn = 0; fn < 4; ++fn) {
        s1[fn] += __shfl_xor(s1[fn], 16); s1[fn] += __shfl_xor(s1[fn], 32);
        s2v[fn] += __shfl_xor(s2v[fn], 16); s2v[fn] += __shfl_xor(s2v[fn], 32);
    }
    if (l < 16) {
#pragma unroll
        for (int fn = 0; fn < 4; ++fn) {
            lsum[wm][wn * 64 + fn * 16 + l] = s1[fn];
            lsq[wm][wn * 64 + fn * 16 + l] = s2v[fn];
        }
    }
    __syncthreads();
    if (t < 256) {
        part1[(size_t)t * NBLK + wgid]        = lsum[0][t] + lsum[1][t];
        part1[(size_t)(C0 + t) * NBLK + wgid] = lsq[0][t] + lsq[1][t];
    }
}

// ---------- stats: one wave per channel, coalesced [channel][block] reads ----------
__global__ void stats_k(const float* __restrict__ part, int nblk, int C,
                        const float* __restrict__ gam, const float* __restrict__ bet,
                        float* __restrict__ sc, float* __restrict__ sh)
{
    const int w = threadIdx.x >> 6, l = threadIdx.x & 63;
    const int o = blockIdx.x * 4 + w;
    if (o >= C) return;
    float s = 0.f, q = 0.f;
    for (int i = l; i < nblk; i += 64) {
        s += part[(size_t)o * nblk + i];
        q += part[(size_t)(C + o) * nblk + i];
    }
#pragma unroll
    for (int r = 32; r; r >>= 1) { s += __shfl_xor(s, r); q += __shfl_xor(q, r); }
    if (l == 0) {
        const float inv = 1.0f / (float)MM;
        float mean = s * inv;
        float var = q * inv - mean * mean;
        float scale = gam[o] * rsqrtf(var + 1e-5f);
        sc[o] = scale;
        sh[o] = bet[o] - mean * scale;
    }
}

// ---------- K5: GEMM2 with BN1+ReLU fused into A staging ----------
__launch_bounds__(256, 4)
__global__ void gemm2_k(const unsigned short* __restrict__ h1, const unsigned short* __restrict__ w1b,
                        const float* __restrict__ sc1, const float* __restrict__ sh1,
                        unsigned short* __restrict__ h2, float* __restrict__ part2)
{
    __shared__ unsigned short Als[128 * 64];
    __shared__ unsigned short Bls[128 * 64];
    __shared__ float scl[256], shl[256];
    __shared__ float lsum[2][128];
    __shared__ float lsq[2][128];

    const int t = threadIdx.x;
    const int wv = t >> 6, l = t & 63, g = l >> 4, lc = l & 15;
    const int wm = wv >> 1, wn = wv & 1;
    const int m0 = blockIdx.x * 128;
    const int sub = t & 7;

    scl[t] = sc1[t]; shl[t] = sh1[t];

    f32x4 acc[4][4];
#pragma unroll
    for (int i = 0; i < 4; ++i)
#pragma unroll
        for (int j = 0; j < 4; ++j) acc[i][j] = (f32x4){0.f, 0.f, 0.f, 0.f};

    for (int ks = 0; ks < 4; ++ks) {
        const int k0 = ks * 64;
        __syncthreads();
        uint4 r[4];
#pragma unroll
        for (int q = 0; q < 4; ++q) {
            int row = q * 32 + (t >> 3);
            r[q] = *(const uint4*)((const char*)h1 + (((size_t)(m0 + row)) * C0 + k0) * 2 + sub * 16);
        }
#pragma unroll
        for (int q = 0; q < 4; ++q) {
            int row = q * 32 + (t >> 3);
            union { uint4 v; unsigned short s[8]; } u, ov;
            u.v = r[q];
#pragma unroll
            for (int i = 0; i < 8; ++i) {
                int k = k0 + sub * 8 + i;
                float f = b2f(u.s[i]);
                ov.s[i] = f2b(fmaxf(0.0f, fmaf(scl[k], f, shl[k])));
            }
            *(uint4*)((char*)Als + row * 128 + ((sub * 16) ^ ((row & 7) << 4))) = ov.v;
        }
#pragma unroll
        for (int q = 0; q < 4; ++q) {
            int o = q * 32 + (t >> 3);
            int bco = (sub * 16) ^ ((o & 7) << 4);
            const char* src = (const char*)w1b + (((size_t)o) * C0 + k0) * 2 + bco;
            char* dst = (char*)Bls + (q * 256 + wv * 64) * 16;
            GLD16(src, dst);
        }
        __syncthreads();
#pragma unroll
        for (int kk = 0; kk < 2; ++kk) {
            short8 af[4], bfr[4];
#pragma unroll
            for (int fm = 0; fm < 4; ++fm) {
                int row = wm * 64 + fm * 16 + lc;
                int bcol = kk * 64 + g * 16;
                af[fm] = *(const short8*)((const char*)Als + row * 128 + (bcol ^ ((row & 7) << 4)));
            }
#pragma unroll
            for (int fn = 0; fn < 4; ++fn) {
                int o = wn * 64 + fn * 16 + lc;
                int bcol = kk * 64 + g * 16;
                bfr[fn] = *(const short8*)((const char*)Bls + o * 128 + (bcol ^ ((o & 7) << 4)));
            }
#pragma unroll
            for (int fm = 0; fm < 4; ++fm)
#pragma unroll
                for (int fn = 0; fn < 4; ++fn)
                    acc[fm][fn] = __builtin_amdgcn_mfma_f32_16x16x32_bf16(af[fm], bfr[fn], acc[fm][fn], 0, 0, 0);
        }
    }

    float s1[4] = {0,0,0,0}, s2v[4] = {0,0,0,0};
#pragma unroll
    for (int fm = 0; fm < 4; ++fm)
#pragma unroll
        for (int fn = 0; fn < 4; ++fn) {
            int row = m0 + wm * 64 + fm * 16 + g * 4;
            int col = wn * 64 + fn * 16 + lc;
#pragma unroll
            for (int j = 0; j < 4; ++j) {
                float v = acc[fm][fn][j];
                h2[((size_t)(row + j)) * C1 + col] = f2b(v);
                s1[fn] += v; s2v[fn] += v * v;
            }
        }
#pragma unroll
    for (int fn = 0; fn < 4; ++fn) {
        s1[fn] += __shfl_xor(s1[fn], 16); s1[fn] += __shfl_xor(s1[fn], 32);
        s2v[fn] += __shfl_xor(s2v[fn], 16); s2v[fn] += __shfl_xor(s2v[fn], 32);
    }
    if (l < 16) {
#pragma unroll
        for (int fn = 0; fn < 4; ++fn) {
            lsum[wm][wn * 64 + fn * 16 + l] = s1[fn];
            lsq[wm][wn * 64 + fn * 16 + l] = s2v[fn];
        }
    }
    __syncthreads();
    if (t < 128) {
        part2[(size_t)t * NBLK + blockIdx.x]        = lsum[0][t] + lsum[1][t];
        part2[(size_t)(C1 + t) * NBLK + blockIdx.x] = lsq[0][t] + lsq[1][t];
    }
}

// ---------- K7: final BN2+ReLU + transpose [b,n,o] -> [b,o,n] f32 ----------
__global__ void finalize_k(const unsigned short* __restrict__ h2,
                           const float* __restrict__ sc, const float* __restrict__ sh,
                           float* __restrict__ out)
{
    __shared__ float tile[64][65];
    const int b = blockIdx.z, o0 = blockIdx.y * 64, n0 = blockIdx.x * 64;
    const int t = threadIdx.x, j = t & 63, i4 = t >> 6;
    const float scv = sc[o0 + j], shv = sh[o0 + j];
#pragma unroll
    for (int p = 0; p < 64; p += 4) {
        int ni = p + i4;
        float f = b2f(h2[((size_t)b * NN + n0 + ni) * C1 + o0 + j]);
        tile[ni][j] = fmaxf(0.0f, fmaf(scv, f, shv));
    }
    __syncthreads();
#pragma unroll
    for (int p = 0; p < 64; p += 4) {
        int oi = p + i4;
        out[((size_t)(b * C1 + o0 + oi)) * NN + n0 + j] = tile[j][oi];
    }
}

// ---------- launch ----------
extern "C" void kernel_launch(void* const* d_in, const int* in_sizes, int n_in,
                              void* d_out, int out_size, void* d_ws, size_t ws_size,
                              hipStream_t stream)
{
    const float* xyz1    = (const float*)d_in[0];
    const float* xyz2    = (const float*)d_in[1];
    const float* points1 = (const float*)d_in[2];
    const float* points2 = (const float*)d_in[3];
    const float* w0      = (const float*)d_in[4];
    const float* g0      = (const float*)d_in[6];
    const float* be0     = (const float*)d_in[7];
    const float* w1      = (const float*)d_in[8];
    const float* g1      = (const float*)d_in[10];
    const float* be1     = (const float*)d_in[11];
    float* out = (float*)d_out;
    char* ws = (char*)d_ws;

    unsigned short* P1T = (unsigned short*)(ws + 0);           // 16777216
    unsigned short* h1  = (unsigned short*)(ws + 16777216);    // 33554432
    unsigned short* P2T = (unsigned short*)(ws + 50331648);    // 8388608
    unsigned short* h2  = (unsigned short*)(ws + 58720256);    // 16777216
    double* trip = (double*)(ws + 75497472);                   // 3145728
    float* wtb   = (float*)(ws + 78643200);                    // 786432
    unsigned short* w0b = (unsigned short*)(ws + 79429632);    // 196608
    unsigned short* w1b = (unsigned short*)(ws + 79626240);    // 65536
    float* part1 = (float*)(ws + 79691776);                    // 1048576
    float* part2 = (float*)(ws + 80740352);                    // 524288
    float* sc1   = (float*)(ws + 81264640);
    float* sh1   = (float*)(ws + 81265664);
    float* sc2   = (float*)(ws + 81266688);
    float* sh2   = (float*)(ws + 81267712);
    // total ws needed: ~81.3 MB

    mega_front_k<<<118 * 64, 256, 0, stream>>>(xyz1, xyz2, points1, points2, w0, w1,
                                               P1T, P2T, w0b, w1b, trip, wtb);
    gemm1_k<<<MM/128, 512, 0, stream>>>(P1T, P2T, trip, wtb, w0b, h1, part1);
    stats_k<<<C0/4, 256, 0, stream>>>(part1, NBLK, C0, g0, be0, sc1, sh1);
    gemm2_k<<<MM/128, 256, 0, stream>>>(h1, w1b, sc1, sh1, h2, part2);
    stats_k<<<C1/4, 256, 0, stream>>>(part2, NBLK, C1, g1, be1, sc2, sh2);
    finalize_k<<<dim3(NN/64, C1/64, BB), 256, 0, stream>>>(h2, sc2, sh2, out);
}